// Round 4
// baseline (700.639 us; speedup 1.0000x reference)
//
#include <hip/hip_runtime.h>

#define DM 256
#define HEADS 8

typedef __attribute__((ext_vector_type(8))) short bf16x8;
typedef __attribute__((ext_vector_type(4))) float f32x4;
typedef unsigned short us16;

__device__ __forceinline__ unsigned short f2bf(float f) {
  unsigned int u = __float_as_uint(f);
  u += 0x7fffu + ((u >> 16) & 1u);          // round-to-nearest-even
  return (unsigned short)(u >> 16);
}
__device__ __forceinline__ float bf2f(unsigned short s) {
  return __uint_as_float(((unsigned int)s) << 16);
}

__device__ __forceinline__ void gload16(const void* g, void* l) {
  __builtin_amdgcn_global_load_lds(
      (const __attribute__((address_space(1))) void*)g,
      (__attribute__((address_space(3))) void*)l, 16, 0, 0);
}

// ---------------- bf16 MFMA GEMM:  C[M x ldc] = A[M x 256] @ W[ldc x 256]^T
// 128x128 tile, 4 waves (2x2), BK=32, global_load_lds staging (m97 structure).
// Cb!=null -> bf16 output (unguarded, padded buffer). Cf!=null -> fp32 + residual R, row<Mreal guard.
__global__ __launch_bounds__(256) void gemm_bf16(
    const us16* __restrict__ A, const us16* __restrict__ W,
    us16* __restrict__ Cb, float* __restrict__ Cf, const float* __restrict__ R,
    int Mreal, int ldc)
{
  __shared__ us16 As[128 * 32];
  __shared__ us16 Bs[128 * 32];
  const int tid = threadIdx.x;
  const int w = tid >> 6, l = tid & 63;
  const int wr = w >> 1, wc = w & 1;
  const int rowBase = blockIdx.x * 128;
  const int colBase = blockIdx.y * 128;
  const int lr = l >> 2;          // staging row within 16-row chunk
  const int lc = (l & 3) * 8;     // staging col (8 bf16 = 16 B)
  f32x4 acc[4][4] = {};

  for (int k0 = 0; k0 < 256; k0 += 32) {
#pragma unroll
    for (int i = 0; i < 2; ++i) {
      const int rchunk = w * 32 + i * 16;          // wave-uniform
      const int r = rchunk + lr;
      gload16(A + (size_t)(rowBase + r) * 256 + k0 + lc, &As[rchunk * 32]);
      gload16(W + (size_t)(colBase + r) * 256 + k0 + lc, &Bs[rchunk * 32]);
    }
    __syncthreads();
    bf16x8 af[4], bfr[4];
#pragma unroll
    for (int m = 0; m < 4; ++m)
      af[m] = *(const bf16x8*)&As[(wr * 64 + m * 16 + (l & 15)) * 32 + (l >> 4) * 8];
#pragma unroll
    for (int n = 0; n < 4; ++n)
      bfr[n] = *(const bf16x8*)&Bs[(wc * 64 + n * 16 + (l & 15)) * 32 + (l >> 4) * 8];
#pragma unroll
    for (int m = 0; m < 4; ++m)
#pragma unroll
      for (int n = 0; n < 4; ++n)
        acc[m][n] = __builtin_amdgcn_mfma_f32_16x16x32_bf16(af[m], bfr[n], acc[m][n], 0, 0, 0);
    __syncthreads();
  }

  // epilogue: C/D layout col=lane&15, row=(lane>>4)*4+j  [m89-verified]
  const int er = (l >> 4) * 4;
  const int ec = l & 15;
#pragma unroll
  for (int m = 0; m < 4; ++m)
#pragma unroll
    for (int n = 0; n < 4; ++n)
#pragma unroll
      for (int j = 0; j < 4; ++j) {
        const int grow = rowBase + wr * 64 + m * 16 + er + j;
        const int gcol = colBase + wc * 64 + n * 16 + ec;
        const float v = acc[m][n][j];
        if (Cf) {
          if (grow < Mreal) {
            const size_t off = (size_t)grow * ldc + gcol;
            Cf[off] = v + R[off];
          }
        } else {
          Cb[(size_t)grow * ldc + gcol] = f2bf(v);
        }
      }
}

// ---------------- fp32 -> bf16 with row padding (pad rows = 0)
__global__ void cvt_pad(const float* __restrict__ in, us16* __restrict__ out,
                        int realRows, int padRows)
{
  const size_t idx = ((size_t)blockIdx.x * 256 + threadIdx.x) * 8;
  if (idx >= (size_t)padRows * 256) return;
  const int row = (int)(idx >> 8);
  bf16x8 o;
  if (row < realRows) {
    const float4 a = *(const float4*)(in + idx);
    const float4 b = *(const float4*)(in + idx + 4);
    o[0] = (short)f2bf(a.x); o[1] = (short)f2bf(a.y);
    o[2] = (short)f2bf(a.z); o[3] = (short)f2bf(a.w);
    o[4] = (short)f2bf(b.x); o[5] = (short)f2bf(b.y);
    o[6] = (short)f2bf(b.z); o[7] = (short)f2bf(b.w);
  } else {
    o = (bf16x8){0, 0, 0, 0, 0, 0, 0, 0};
  }
  *(bf16x8*)(out + idx) = o;
}

// stacked [Wk; Wv] -> bf16 [512 x 256]
__global__ void cvt_wkv(const float* __restrict__ Wk, const float* __restrict__ Wv,
                        us16* __restrict__ out)
{
  const size_t idx = ((size_t)blockIdx.x * 256 + threadIdx.x) * 8;
  if (idx >= (size_t)512 * 256) return;
  const float* src = (idx < (size_t)256 * 256) ? (Wk + idx) : (Wv + idx - 256 * 256);
  const float4 a = *(const float4*)(src);
  const float4 b = *(const float4*)(src + 4);
  bf16x8 o;
  o[0] = (short)f2bf(a.x); o[1] = (short)f2bf(a.y);
  o[2] = (short)f2bf(a.z); o[3] = (short)f2bf(a.w);
  o[4] = (short)f2bf(b.x); o[5] = (short)f2bf(b.y);
  o[6] = (short)f2bf(b.z); o[7] = (short)f2bf(b.w);
  *(bf16x8*)(out + idx) = o;
}

// ---------------- CSR build ----------------
__global__ void hist_kernel(const int* __restrict__ a_idx, int* __restrict__ counts, int E)
{
  const int e = blockIdx.x * 256 + threadIdx.x;
  if (e < E) atomicAdd(&counts[a_idx[e]], 1);
}

// block-level exclusive scan + one atomic base per block (segments need no global order)
__global__ __launch_bounds__(256) void scan_offs(const int* __restrict__ counts,
    int* __restrict__ offs, int* __restrict__ cursor, int* __restrict__ total, int n)
{
  __shared__ int buf[256];
  __shared__ int sbase;
  const int t = threadIdx.x;
  const int i = blockIdx.x * 256 + t;
  const int v = (i < n) ? counts[i] : 0;
  buf[t] = v;
  __syncthreads();
#pragma unroll
  for (int off = 1; off < 256; off <<= 1) {
    const int x = (t >= off) ? buf[t - off] : 0;
    __syncthreads();
    buf[t] += x;
    __syncthreads();
  }
  const int incl = buf[t];
  if (t == 255) sbase = atomicAdd(total, incl);
  __syncthreads();
  if (i < n) {
    const int excl = sbase + incl - v;
    offs[i] = excl;
    cursor[i] = excl;
  }
}

__global__ void scatter_kernel(const int* __restrict__ a_idx,
    int* __restrict__ cursor, int* __restrict__ elist, int E)
{
  const int e = blockIdx.x * 256 + threadIdx.x;
  if (e < E) elist[atomicAdd(&cursor[a_idx[e]], 1)] = e;
}

// ---------------- edge attention: 1 block / query node, 8 heads x 32 lanes.
// softmax without max-shift == reference (logits ~ N(0,1), fp32-safe).
__global__ __launch_bounds__(256) void edge_attn(
    const us16* __restrict__ Qb, const us16* __restrict__ KVb,
    const int* __restrict__ b_idx, const int* __restrict__ offs,
    const int* __restrict__ counts, const int* __restrict__ elist,
    us16* __restrict__ outb)
{
  const int a = blockIdx.x;
  const int tid = threadIdx.x;            // h = tid>>5, d = tid&31
  const float q = bf2f(Qb[(size_t)a * 256 + tid]);
  const int start = offs[a];
  const int cnt = counts[a];
  const float scale = 0.17677669529663687f;   // 1/sqrt(32)
  float acc = 0.f, ssum = 0.f;
  for (int i = 0; i < cnt; ++i) {
    const int e = elist[start + i];
    const int b = b_idx[e];
    const us16* kv = KVb + (size_t)b * 512;
    float p = q * bf2f(kv[tid]);
#pragma unroll
    for (int m = 16; m >= 1; m >>= 1) p += __shfl_xor(p, m, 32);
    const float ex = __expf(p * scale);
    ssum += ex;
    acc = fmaf(ex, bf2f(kv[256 + tid]), acc);
  }
  outb[(size_t)a * 256 + tid] = f2bf(cnt > 0 ? acc / ssum : 0.f);
}

extern "C" void kernel_launch(void* const* d_in, const int* in_sizes, int n_in,
                              void* d_out, int out_size, void* d_ws, size_t ws_size,
                              hipStream_t stream)
{
  const float* Fa    = (const float*)d_in[0];
  const float* Fb    = (const float*)d_in[1];
  const int*   a_idx = (const int*)d_in[2];
  const int*   b_idx = (const int*)d_in[3];
  const float* Wq    = (const float*)d_in[4];
  const float* Wk    = (const float*)d_in[5];
  const float* Wv    = (const float*)d_in[6];
  const float* Wproj = (const float*)d_in[7];
  float* out = (float*)d_out;

  const int NA = in_sizes[0] / DM;
  const int NB = in_sizes[1] / DM;
  const int E  = in_sizes[2];
  const int MAp = (NA + 127) & ~127;
  const int NBp = (NB + 127) & ~127;

  // workspace layout (bf16 buffers then int buffers)
  us16* Fa_bf  = (us16*)d_ws;                       // MAp*256
  us16* Fb_bf  = Fa_bf  + (size_t)MAp * 256;        // NBp*256
  us16* Qbf    = Fb_bf  + (size_t)NBp * 256;        // MAp*256
  us16* KVbf   = Qbf    + (size_t)MAp * 256;        // NBp*512 (K | V per row)
  us16* ATbf   = KVbf   + (size_t)NBp * 512;        // MAp*256
  us16* Wq_bf  = ATbf   + (size_t)MAp * 256;        // 256*256
  us16* Wkv_bf = Wq_bf  + 256 * 256;                // 512*256
  us16* Wp_bf  = Wkv_bf + 512 * 256;                // 256*256
  int* total   = (int*)(Wp_bf + 256 * 256);
  int* counts  = total + 1;
  int* offs    = counts + NA;
  int* cursor  = offs + NA;
  int* elist   = cursor + NA;

  hipMemsetAsync(total, 0, (size_t)(NA + 1) * sizeof(int), stream);

  // conversions
  cvt_pad<<<MAp / 8, 256, 0, stream>>>(Fa, Fa_bf, NA, MAp);
  cvt_pad<<<NBp / 8, 256, 0, stream>>>(Fb, Fb_bf, NB, NBp);
  cvt_pad<<<32, 256, 0, stream>>>(Wq, Wq_bf, 256, 256);
  cvt_wkv<<<64, 256, 0, stream>>>(Wk, Wv, Wkv_bf);
  cvt_pad<<<32, 256, 0, stream>>>(Wproj, Wp_bf, 256, 256);

  // CSR build (independent of GEMMs, stream-serial anyway)
  hist_kernel<<<(E + 255) / 256, 256, 0, stream>>>(a_idx, counts, E);
  scan_offs<<<(NA + 255) / 256, 256, 0, stream>>>(counts, offs, cursor, total, NA);
  scatter_kernel<<<(E + 255) / 256, 256, 0, stream>>>(a_idx, cursor, elist, E);

  // projections
  dim3 blk(256);
  gemm_bf16<<<dim3(MAp / 128, 2), blk, 0, stream>>>(Fa_bf, Wq_bf, Qbf, nullptr, nullptr, NA, 256);
  gemm_bf16<<<dim3(NBp / 128, 4), blk, 0, stream>>>(Fb_bf, Wkv_bf, KVbf, nullptr, nullptr, NB, 512);

  // attention
  edge_attn<<<NA, 256, 0, stream>>>(Qbf, KVbf, b_idx, offs, counts, elist, ATbf);

  // output projection + residual (fp32 out, guarded)
  gemm_bf16<<<dim3(MAp / 128, 2), blk, 0, stream>>>(ATbf, Wp_bf, nullptr, out, Fa, NA, 256);
}

// Round 5
// 502.511 us; speedup vs baseline: 1.3943x; 1.3943x over previous
//
#include <hip/hip_runtime.h>

#define DM 256
#define HEADS 8

typedef __attribute__((ext_vector_type(8))) short bf16x8;
typedef __attribute__((ext_vector_type(4))) float f32x4;
typedef __attribute__((ext_vector_type(4))) unsigned short us16x4;
typedef unsigned short us16;

__device__ __forceinline__ unsigned short f2bf(float f) {
  unsigned int u = __float_as_uint(f);
  u += 0x7fffu + ((u >> 16) & 1u);          // round-to-nearest-even
  return (unsigned short)(u >> 16);
}
__device__ __forceinline__ float bf2f(unsigned short s) {
  return __uint_as_float(((unsigned int)s) << 16);
}

__device__ __forceinline__ void gload16(const void* g, void* l) {
  __builtin_amdgcn_global_load_lds(
      (const __attribute__((address_space(1))) void*)g,
      (__attribute__((address_space(3))) void*)l, 16, 0, 0);
}

// ---------------- bf16 MFMA GEMM:  C[M x ldc] = A[M x 256] @ W[ldc x 256]^T
// 128x128 tile, 4 waves (2x2), BK=32, global_load_lds staging (m97 structure).
__global__ __launch_bounds__(256) void gemm_bf16(
    const us16* __restrict__ A, const us16* __restrict__ W,
    us16* __restrict__ Cb, float* __restrict__ Cf, const float* __restrict__ R,
    int Mreal, int ldc)
{
  __shared__ us16 As[128 * 32];
  __shared__ us16 Bs[128 * 32];
  const int tid = threadIdx.x;
  const int w = tid >> 6, l = tid & 63;
  const int wr = w >> 1, wc = w & 1;
  const int rowBase = blockIdx.x * 128;
  const int colBase = blockIdx.y * 128;
  const int lr = l >> 2;          // staging row within 16-row chunk
  const int lc = (l & 3) * 8;     // staging col (8 bf16 = 16 B)
  f32x4 acc[4][4] = {};

  for (int k0 = 0; k0 < 256; k0 += 32) {
#pragma unroll
    for (int i = 0; i < 2; ++i) {
      const int rchunk = w * 32 + i * 16;          // wave-uniform
      const int r = rchunk + lr;
      gload16(A + (size_t)(rowBase + r) * 256 + k0 + lc, &As[rchunk * 32]);
      gload16(W + (size_t)(colBase + r) * 256 + k0 + lc, &Bs[rchunk * 32]);
    }
    __syncthreads();
    bf16x8 af[4], bfr[4];
#pragma unroll
    for (int m = 0; m < 4; ++m)
      af[m] = *(const bf16x8*)&As[(wr * 64 + m * 16 + (l & 15)) * 32 + (l >> 4) * 8];
#pragma unroll
    for (int n = 0; n < 4; ++n)
      bfr[n] = *(const bf16x8*)&Bs[(wc * 64 + n * 16 + (l & 15)) * 32 + (l >> 4) * 8];
#pragma unroll
    for (int m = 0; m < 4; ++m)
#pragma unroll
      for (int n = 0; n < 4; ++n)
        acc[m][n] = __builtin_amdgcn_mfma_f32_16x16x32_bf16(af[m], bfr[n], acc[m][n], 0, 0, 0);
    __syncthreads();
  }

  // epilogue: C/D layout col=lane&15, row=(lane>>4)*4+j  [m89-verified]
  const int er = (l >> 4) * 4;
  const int ec = l & 15;
#pragma unroll
  for (int m = 0; m < 4; ++m)
#pragma unroll
    for (int n = 0; n < 4; ++n)
#pragma unroll
      for (int j = 0; j < 4; ++j) {
        const int grow = rowBase + wr * 64 + m * 16 + er + j;
        const int gcol = colBase + wc * 64 + n * 16 + ec;
        const float v = acc[m][n][j];
        if (Cf) {
          if (grow < Mreal) {
            const size_t off = (size_t)grow * ldc + gcol;
            Cf[off] = v + R[off];
          }
        } else {
          Cb[(size_t)grow * ldc + gcol] = f2bf(v);
        }
      }
}

// ---------------- fp32 -> bf16 with row padding (pad rows = 0)
__global__ void cvt_pad(const float* __restrict__ in, us16* __restrict__ out,
                        int realRows, int padRows)
{
  const size_t idx = ((size_t)blockIdx.x * 256 + threadIdx.x) * 8;
  if (idx >= (size_t)padRows * 256) return;
  const int row = (int)(idx >> 8);
  bf16x8 o;
  if (row < realRows) {
    const float4 a = *(const float4*)(in + idx);
    const float4 b = *(const float4*)(in + idx + 4);
    o[0] = (short)f2bf(a.x); o[1] = (short)f2bf(a.y);
    o[2] = (short)f2bf(a.z); o[3] = (short)f2bf(a.w);
    o[4] = (short)f2bf(b.x); o[5] = (short)f2bf(b.y);
    o[6] = (short)f2bf(b.z); o[7] = (short)f2bf(b.w);
  } else {
    o = (bf16x8){0, 0, 0, 0, 0, 0, 0, 0};
  }
  *(bf16x8*)(out + idx) = o;
}

// stacked [Wk; Wv] -> bf16 [512 x 256]
__global__ void cvt_wkv(const float* __restrict__ Wk, const float* __restrict__ Wv,
                        us16* __restrict__ out)
{
  const size_t idx = ((size_t)blockIdx.x * 256 + threadIdx.x) * 8;
  if (idx >= (size_t)512 * 256) return;
  const float* src = (idx < (size_t)256 * 256) ? (Wk + idx) : (Wv + idx - 256 * 256);
  const float4 a = *(const float4*)(src);
  const float4 b = *(const float4*)(src + 4);
  bf16x8 o;
  o[0] = (short)f2bf(a.x); o[1] = (short)f2bf(a.y);
  o[2] = (short)f2bf(a.z); o[3] = (short)f2bf(a.w);
  o[4] = (short)f2bf(b.x); o[5] = (short)f2bf(b.y);
  o[6] = (short)f2bf(b.z); o[7] = (short)f2bf(b.w);
  *(bf16x8*)(out + idx) = o;
}

// ---------------- CSR build ----------------
__global__ void hist_kernel(const int* __restrict__ a_idx, int* __restrict__ counts, int E)
{
  const int e = blockIdx.x * 256 + threadIdx.x;
  if (e < E) atomicAdd(&counts[a_idx[e]], 1);
}

// block-level exclusive scan + one atomic base per block (segments need no global order)
__global__ __launch_bounds__(256) void scan_offs(const int* __restrict__ counts,
    int* __restrict__ offs, int* __restrict__ cursor, int* __restrict__ total, int n)
{
  __shared__ int buf[256];
  __shared__ int sbase;
  const int t = threadIdx.x;
  const int i = blockIdx.x * 256 + t;
  const int v = (i < n) ? counts[i] : 0;
  buf[t] = v;
  __syncthreads();
#pragma unroll
  for (int off = 1; off < 256; off <<= 1) {
    const int x = (t >= off) ? buf[t - off] : 0;
    __syncthreads();
    buf[t] += x;
    __syncthreads();
  }
  const int incl = buf[t];
  if (t == 255) sbase = atomicAdd(total, incl);
  __syncthreads();
  if (i < n) {
    const int excl = sbase + incl - v;
    offs[i] = excl;
    cursor[i] = excl;
  }
}

// fuse the b_idx gather into the scatter: attn never needs the edge id, only b.
__global__ void scatter_kernel(const int* __restrict__ a_idx, const int* __restrict__ b_idx,
    int* __restrict__ cursor, int* __restrict__ bel, int E)
{
  const int e = blockIdx.x * 256 + threadIdx.x;
  if (e < E) bel[atomicAdd(&cursor[a_idx[e]], 1)] = b_idx[e];
}

// ---------------- edge attention: ONE WAVE per query node.
// lane = h*8 + j ; lane owns dims [j*4 .. j*4+3] of head h (ushort4 = 8B loads).
// dot reduce = 3-step butterfly over the 8-lane head group.
// softmax without max-shift == reference (logits ~ N(0,1), fp32-safe).
__global__ __launch_bounds__(256) void edge_attn(
    const us16* __restrict__ Qb, const us16* __restrict__ KVb,
    const int* __restrict__ offs, const int* __restrict__ counts,
    const int* __restrict__ bel, us16* __restrict__ outb, int NA)
{
  const int a = blockIdx.x * 4 + (threadIdx.x >> 6);
  if (a >= NA) return;
  const int l = threadIdx.x & 63;
  const float scale = 0.17677669529663687f;   // 1/sqrt(32)

  const us16x4 q4 = *(const us16x4*)(Qb + (size_t)a * 256 + l * 4);
  float q0 = bf2f(q4[0]), q1 = bf2f(q4[1]), q2 = bf2f(q4[2]), q3 = bf2f(q4[3]);

  const int start = offs[a];
  const int cnt = counts[a];
  float acc0 = 0.f, acc1 = 0.f, acc2 = 0.f, acc3 = 0.f, ssum = 0.f;

  // 2-deep pipeline over the KV gather
  us16x4 kc = {0, 0, 0, 0}, vc = {0, 0, 0, 0};
  if (cnt > 0) {
    const us16* kv = KVb + (size_t)bel[start] * 512;
    kc = *(const us16x4*)(kv + l * 4);
    vc = *(const us16x4*)(kv + 256 + l * 4);
  }
  for (int i = 0; i < cnt; ++i) {
    us16x4 kn = kc, vn = vc;
    if (i + 1 < cnt) {
      const us16* kv = KVb + (size_t)bel[start + i + 1] * 512;
      kn = *(const us16x4*)(kv + l * 4);
      vn = *(const us16x4*)(kv + 256 + l * 4);
    }
    float p = q0 * bf2f(kc[0]);
    p = fmaf(q1, bf2f(kc[1]), p);
    p = fmaf(q2, bf2f(kc[2]), p);
    p = fmaf(q3, bf2f(kc[3]), p);
    p += __shfl_xor(p, 1, 64);
    p += __shfl_xor(p, 2, 64);
    p += __shfl_xor(p, 4, 64);
    const float ex = __expf(p * scale);
    ssum += ex;
    acc0 = fmaf(ex, bf2f(vc[0]), acc0);
    acc1 = fmaf(ex, bf2f(vc[1]), acc1);
    acc2 = fmaf(ex, bf2f(vc[2]), acc2);
    acc3 = fmaf(ex, bf2f(vc[3]), acc3);
    kc = kn; vc = vn;
  }

  const float inv = (cnt > 0) ? 1.f / ssum : 0.f;
  us16x4 o;
  o[0] = f2bf(acc0 * inv); o[1] = f2bf(acc1 * inv);
  o[2] = f2bf(acc2 * inv); o[3] = f2bf(acc3 * inv);
  *(us16x4*)(outb + (size_t)a * 256 + l * 4) = o;
}

extern "C" void kernel_launch(void* const* d_in, const int* in_sizes, int n_in,
                              void* d_out, int out_size, void* d_ws, size_t ws_size,
                              hipStream_t stream)
{
  const float* Fa    = (const float*)d_in[0];
  const float* Fb    = (const float*)d_in[1];
  const int*   a_idx = (const int*)d_in[2];
  const int*   b_idx = (const int*)d_in[3];
  const float* Wq    = (const float*)d_in[4];
  const float* Wk    = (const float*)d_in[5];
  const float* Wv    = (const float*)d_in[6];
  const float* Wproj = (const float*)d_in[7];
  float* out = (float*)d_out;

  const int NA = in_sizes[0] / DM;
  const int NB = in_sizes[1] / DM;
  const int E  = in_sizes[2];
  const int MAp = (NA + 127) & ~127;
  const int NBp = (NB + 127) & ~127;

  // workspace layout (bf16 buffers then int buffers)
  us16* Fa_bf  = (us16*)d_ws;                       // MAp*256
  us16* Fb_bf  = Fa_bf  + (size_t)MAp * 256;        // NBp*256
  us16* Qbf    = Fb_bf  + (size_t)NBp * 256;        // MAp*256
  us16* KVbf   = Qbf    + (size_t)MAp * 256;        // NBp*512 (K | V per row)
  us16* ATbf   = KVbf   + (size_t)NBp * 512;        // MAp*256
  us16* Wq_bf  = ATbf   + (size_t)MAp * 256;        // 256*256
  us16* Wkv_bf = Wq_bf  + 256 * 256;                // 512*256
  us16* Wp_bf  = Wkv_bf + 512 * 256;                // 256*256
  int* total   = (int*)(Wp_bf + 256 * 256);
  int* counts  = total + 1;
  int* offs    = counts + NA;
  int* cursor  = offs + NA;
  int* bel     = cursor + NA;

  hipMemsetAsync(total, 0, (size_t)(NA + 1) * sizeof(int), stream);

  // conversions
  cvt_pad<<<MAp / 8, 256, 0, stream>>>(Fa, Fa_bf, NA, MAp);
  cvt_pad<<<NBp / 8, 256, 0, stream>>>(Fb, Fb_bf, NB, NBp);
  cvt_pad<<<32, 256, 0, stream>>>(Wq, Wq_bf, 256, 256);
  cvt_wkv<<<64, 256, 0, stream>>>(Wk, Wv, Wkv_bf);
  cvt_pad<<<32, 256, 0, stream>>>(Wproj, Wp_bf, 256, 256);

  // CSR build
  hist_kernel<<<(E + 255) / 256, 256, 0, stream>>>(a_idx, counts, E);
  scan_offs<<<(NA + 255) / 256, 256, 0, stream>>>(counts, offs, cursor, total, NA);
  scatter_kernel<<<(E + 255) / 256, 256, 0, stream>>>(a_idx, b_idx, cursor, bel, E);

  // projections
  dim3 blk(256);
  gemm_bf16<<<dim3(MAp / 128, 2), blk, 0, stream>>>(Fa_bf, Wq_bf, Qbf, nullptr, nullptr, NA, 256);
  gemm_bf16<<<dim3(NBp / 128, 4), blk, 0, stream>>>(Fb_bf, Wkv_bf, KVbf, nullptr, nullptr, NB, 512);

  // attention: one wave per node, 4 nodes per block
  edge_attn<<<(NA + 3) / 4, 256, 0, stream>>>(Qbf, KVbf, offs, counts, bel, ATbf, NA);

  // output projection + residual (fp32 out, guarded)
  gemm_bf16<<<dim3(MAp / 128, 2), blk, 0, stream>>>(ATbf, Wp_bf, nullptr, out, Fa, NA, 256);
}

// Round 6
// 437.928 us; speedup vs baseline: 1.5999x; 1.1475x over previous
//
#include <hip/hip_runtime.h>

#define DM 256

typedef __attribute__((ext_vector_type(8))) short bf16x8;
typedef __attribute__((ext_vector_type(4))) float f32x4;
typedef __attribute__((ext_vector_type(4))) unsigned short us16x4;
typedef unsigned short us16;

__device__ __forceinline__ unsigned short f2bf(float f) {
  unsigned int u = __float_as_uint(f);
  u += 0x7fffu + ((u >> 16) & 1u);          // round-to-nearest-even
  return (unsigned short)(u >> 16);
}
__device__ __forceinline__ float bf2f(unsigned short s) {
  return __uint_as_float(((unsigned int)s) << 16);
}

__device__ __forceinline__ void gload16(const void* g, void* l) {
  __builtin_amdgcn_global_load_lds(
      (const __attribute__((address_space(1))) void*)g,
      (__attribute__((address_space(3))) void*)l, 16, 0, 0);
}

// ---------------- bf16 MFMA GEMM:  C[M x ldc] = A[M x 256] @ W[. x 256]^T
// 128x256 tile, 8 waves (2x4), BK=32. B via global_load_lds; A reg-staged
// (optionally fused fp32->bf16 convert). Fragment/epilogue math identical to
// the verified round-5 kernel (64 B LDS rows, m89 C/D layout).
template <bool A_FP32>
__global__ __launch_bounds__(512) void gemm_bf16(
    const void* __restrict__ Avoid, const us16* __restrict__ W,
    us16* __restrict__ Cb, float* __restrict__ Cf, const float* __restrict__ R,
    int Mreal, int ldc)
{
  __shared__ us16 As[128 * 32];
  __shared__ us16 Bs[256 * 32];
  const int tid = threadIdx.x;
  const int w = tid >> 6, l = tid & 63;
  const int wr = w >> 2, wc = w & 3;          // wave grid 2 x 4
  const int rowBase = blockIdx.x * 128;
  const int colBase = blockIdx.y * 256;
  const int ar = tid >> 2, ac = (tid & 3) * 8;   // A staging: row, col(8 bf16)
  f32x4 acc[4][4] = {};

  for (int k0 = 0; k0 < 256; k0 += 32) {
    // B: 2 gload rounds per wave, 16 rows (1 KB) each; wave-uniform LDS base
#pragma unroll
    for (int j = 0; j < 2; ++j) {
      const int r0 = (w * 2 + j) * 16;
      gload16(W + (size_t)(colBase + r0 + (l >> 2)) * 256 + k0 + (l & 3) * 8,
              &Bs[r0 * 32]);
    }
    // A: reg-stage (+convert), guarded -> zero pad rows
    {
      const int grow = rowBase + ar;
      bf16x8 av = (bf16x8){0, 0, 0, 0, 0, 0, 0, 0};
      if (grow < Mreal) {
        if (A_FP32) {
          const float* Af = (const float*)Avoid;
          const float4 x = *(const float4*)(Af + (size_t)grow * 256 + k0 + ac);
          const float4 y = *(const float4*)(Af + (size_t)grow * 256 + k0 + ac + 4);
          av[0] = (short)f2bf(x.x); av[1] = (short)f2bf(x.y);
          av[2] = (short)f2bf(x.z); av[3] = (short)f2bf(x.w);
          av[4] = (short)f2bf(y.x); av[5] = (short)f2bf(y.y);
          av[6] = (short)f2bf(y.z); av[7] = (short)f2bf(y.w);
        } else {
          const us16* Ab = (const us16*)Avoid;
          av = *(const bf16x8*)(Ab + (size_t)grow * 256 + k0 + ac);
        }
      }
      *(bf16x8*)&As[ar * 32 + ac] = av;
    }
    __syncthreads();
    bf16x8 af[4], bfr[4];
#pragma unroll
    for (int m = 0; m < 4; ++m)
      af[m] = *(const bf16x8*)&As[(wr * 64 + m * 16 + (l & 15)) * 32 + (l >> 4) * 8];
#pragma unroll
    for (int n = 0; n < 4; ++n)
      bfr[n] = *(const bf16x8*)&Bs[(wc * 64 + n * 16 + (l & 15)) * 32 + (l >> 4) * 8];
#pragma unroll
    for (int m = 0; m < 4; ++m)
#pragma unroll
      for (int n = 0; n < 4; ++n)
        acc[m][n] = __builtin_amdgcn_mfma_f32_16x16x32_bf16(af[m], bfr[n], acc[m][n], 0, 0, 0);
    __syncthreads();
  }

  // epilogue: C/D layout col=lane&15, row=(lane>>4)*4+j  [m89-verified]
  const int er = (l >> 4) * 4;
  const int ec = l & 15;
#pragma unroll
  for (int m = 0; m < 4; ++m)
#pragma unroll
    for (int n = 0; n < 4; ++n)
#pragma unroll
      for (int j = 0; j < 4; ++j) {
        const int grow = rowBase + wr * 64 + m * 16 + er + j;
        const int gcol = colBase + wc * 64 + n * 16 + ec;
        const float v = acc[m][n][j];
        if (Cf) {
          if (grow < Mreal) {
            const size_t off = (size_t)grow * ldc + gcol;
            Cf[off] = v + R[off];
          }
        } else {
          Cb[(size_t)grow * ldc + gcol] = f2bf(v);
        }
      }
}

// ---------------- all 4 weight matrices -> one bf16 [1024 x 256] buffer
__global__ void cvt_weights(const float* __restrict__ Wq, const float* __restrict__ Wk,
                            const float* __restrict__ Wv, const float* __restrict__ Wp,
                            us16* __restrict__ out)
{
  const int g = blockIdx.x * 256 + threadIdx.x;      // 32768 threads
  const size_t e = (size_t)g * 8;
  const int sel = (int)(e >> 16);
  const float* src = (sel == 0) ? Wq : (sel == 1) ? Wk : (sel == 2) ? Wv : Wp;
  const size_t loc = e & 65535;
  const float4 x = *(const float4*)(src + loc);
  const float4 y = *(const float4*)(src + loc + 4);
  bf16x8 o;
  o[0] = (short)f2bf(x.x); o[1] = (short)f2bf(x.y);
  o[2] = (short)f2bf(x.z); o[3] = (short)f2bf(x.w);
  o[4] = (short)f2bf(y.x); o[5] = (short)f2bf(y.y);
  o[6] = (short)f2bf(y.z); o[7] = (short)f2bf(y.w);
  *(bf16x8*)(out + e) = o;
}

// ---------------- CSR build ----------------
__global__ void hist_kernel(const int* __restrict__ a_idx, int* __restrict__ counts, int E)
{
  const int e = blockIdx.x * 256 + threadIdx.x;
  if (e < E) atomicAdd(&counts[a_idx[e]], 1);
}

__global__ __launch_bounds__(256) void scan_offs(const int* __restrict__ counts,
    int* __restrict__ offs, int* __restrict__ cursor, int* __restrict__ total, int n)
{
  __shared__ int buf[256];
  __shared__ int sbase;
  const int t = threadIdx.x;
  const int i = blockIdx.x * 256 + t;
  const int v = (i < n) ? counts[i] : 0;
  buf[t] = v;
  __syncthreads();
#pragma unroll
  for (int off = 1; off < 256; off <<= 1) {
    const int x = (t >= off) ? buf[t - off] : 0;
    __syncthreads();
    buf[t] += x;
    __syncthreads();
  }
  const int incl = buf[t];
  if (t == 255) sbase = atomicAdd(total, incl);
  __syncthreads();
  if (i < n) {
    const int excl = sbase + incl - v;
    offs[i] = excl;
    cursor[i] = excl;
  }
}

// fuse the b_idx gather into the scatter: attn only ever needs b, not e.
__global__ void scatter_kernel(const int* __restrict__ a_idx, const int* __restrict__ b_idx,
    int* __restrict__ cursor, int* __restrict__ bel, int E)
{
  const int e = blockIdx.x * 256 + threadIdx.x;
  if (e < E) bel[atomicAdd(&cursor[a_idx[e]], 1)] = b_idx[e];
}

// ---------------- edge attention: ONE WAVE per query node, 4-deep pipeline.
// lane = h*8 + j ; lane owns dims [j*4 .. j*4+3] of head h (8 B loads).
// Prefetch indices are clamped (branchless loads), accumulation guarded by
// the wave-uniform j<cnt predicate. softmax without max-shift == reference.
#define ATTN_STEP(K, V, J)                                     \
  if ((J) < cnt) {                                             \
    float p = q0 * bf2f(K[0]);                                 \
    p = fmaf(q1, bf2f(K[1]), p);                               \
    p = fmaf(q2, bf2f(K[2]), p);                               \
    p = fmaf(q3, bf2f(K[3]), p);                               \
    p += __shfl_xor(p, 1, 64);                                 \
    p += __shfl_xor(p, 2, 64);                                 \
    p += __shfl_xor(p, 4, 64);                                 \
    const float ex = __expf(p * scale);                        \
    ssum += ex;                                                \
    acc0 = fmaf(ex, bf2f(V[0]), acc0);                         \
    acc1 = fmaf(ex, bf2f(V[1]), acc1);                         \
    acc2 = fmaf(ex, bf2f(V[2]), acc2);                         \
    acc3 = fmaf(ex, bf2f(V[3]), acc3);                         \
  }

#define ATTN_LOAD(K, V, IDX)                                   \
  {                                                            \
    const us16* kv = KVb + (size_t)bel[start + (IDX)] * 512;   \
    K = *(const us16x4*)(kv + l * 4);                          \
    V = *(const us16x4*)(kv + 256 + l * 4);                    \
  }

__global__ __launch_bounds__(256) void edge_attn(
    const us16* __restrict__ Qb, const us16* __restrict__ KVb,
    const int* __restrict__ offs, const int* __restrict__ counts,
    const int* __restrict__ bel, us16* __restrict__ outb, int NA)
{
  const int a = blockIdx.x * 4 + (threadIdx.x >> 6);
  if (a >= NA) return;
  const int l = threadIdx.x & 63;
  const float scale = 0.17677669529663687f;   // 1/sqrt(32)

  const us16x4 q4 = *(const us16x4*)(Qb + (size_t)a * 256 + l * 4);
  const float q0 = bf2f(q4[0]), q1 = bf2f(q4[1]), q2 = bf2f(q4[2]), q3 = bf2f(q4[3]);

  const int start = offs[a];
  const int cnt = counts[a];
  float acc0 = 0.f, acc1 = 0.f, acc2 = 0.f, acc3 = 0.f, ssum = 0.f;

  if (cnt > 0) {
    const int last = cnt - 1;
    us16x4 ka, va, kb, vb, kc, vc, kd, vd;
    ATTN_LOAD(ka, va, 0)
    ATTN_LOAD(kb, vb, min(1, last))
    ATTN_LOAD(kc, vc, min(2, last))
    ATTN_LOAD(kd, vd, min(3, last))
    for (int i = 0; i < cnt; i += 4) {
      us16x4 na, xa, nb, xb, nc, xc, nd, xd;
      ATTN_LOAD(na, xa, min(i + 4, last))
      ATTN_LOAD(nb, xb, min(i + 5, last))
      ATTN_LOAD(nc, xc, min(i + 6, last))
      ATTN_LOAD(nd, xd, min(i + 7, last))
      ATTN_STEP(ka, va, i + 0)
      ATTN_STEP(kb, vb, i + 1)
      ATTN_STEP(kc, vc, i + 2)
      ATTN_STEP(kd, vd, i + 3)
      ka = na; va = xa; kb = nb; vb = xb;
      kc = nc; vc = xc; kd = nd; vd = xd;
    }
  }

  const float inv = (cnt > 0) ? 1.f / ssum : 0.f;
  us16x4 o;
  o[0] = f2bf(acc0 * inv); o[1] = f2bf(acc1 * inv);
  o[2] = f2bf(acc2 * inv); o[3] = f2bf(acc3 * inv);
  *(us16x4*)(outb + (size_t)a * 256 + l * 4) = o;
}

extern "C" void kernel_launch(void* const* d_in, const int* in_sizes, int n_in,
                              void* d_out, int out_size, void* d_ws, size_t ws_size,
                              hipStream_t stream)
{
  const float* Fa    = (const float*)d_in[0];
  const float* Fb    = (const float*)d_in[1];
  const int*   a_idx = (const int*)d_in[2];
  const int*   b_idx = (const int*)d_in[3];
  const float* Wq    = (const float*)d_in[4];
  const float* Wk    = (const float*)d_in[5];
  const float* Wv    = (const float*)d_in[6];
  const float* Wproj = (const float*)d_in[7];
  float* out = (float*)d_out;

  const int NA = in_sizes[0] / DM;
  const int NB = in_sizes[1] / DM;
  const int E  = in_sizes[2];
  const int MAp = (NA + 127) & ~127;
  const int NBp = (NB + 127) & ~127;

  // workspace: Qbf | KVbf | ATbf | W_all | ints
  us16* Qbf   = (us16*)d_ws;                        // MAp*256
  us16* KVbf  = Qbf   + (size_t)MAp * 256;          // NBp*512 (K | V per row)
  us16* ATbf  = KVbf  + (size_t)NBp * 512;          // MAp*256
  us16* W_all = ATbf  + (size_t)MAp * 256;          // 1024*256: [Wq;Wk;Wv;Wp]
  int* total  = (int*)(W_all + 1024 * 256);
  int* counts = total + 1;
  int* offs   = counts + NA;
  int* cursor = offs + NA;
  int* bel    = cursor + NA;

  hipMemsetAsync(total, 0, (size_t)(NA + 1) * sizeof(int), stream);

  cvt_weights<<<128, 256, 0, stream>>>(Wq, Wk, Wv, Wproj, W_all);

  // CSR build
  hist_kernel<<<(E + 255) / 256, 256, 0, stream>>>(a_idx, counts, E);
  scan_offs<<<(NA + 255) / 256, 256, 0, stream>>>(counts, offs, cursor, total, NA);
  scatter_kernel<<<(E + 255) / 256, 256, 0, stream>>>(a_idx, b_idx, cursor, bel, E);

  // projections (fp32 A fused-converted in staging)
  gemm_bf16<true><<<dim3(MAp / 128, 1), 512, 0, stream>>>(Fa, W_all, Qbf, nullptr, nullptr, NA, 256);
  gemm_bf16<true><<<dim3(NBp / 128, 2), 512, 0, stream>>>(Fb, W_all + 256 * 256, KVbf, nullptr, nullptr, NB, 512);

  // attention: one wave per node, 4 nodes per block
  edge_attn<<<(NA + 3) / 4, 256, 0, stream>>>(Qbf, KVbf, offs, counts, bel, ATbf, NA);

  // output projection + residual (fp32 out, guarded)
  gemm_bf16<false><<<dim3(MAp / 128, 1), 512, 0, stream>>>(ATbf, W_all + 768 * 256, nullptr, out, Fa, NA, 256);
}